// Round 4
// baseline (87.948 us; speedup 1.0000x reference)
//
#include <hip/hip_runtime.h>

// Problem constants (match reference)
#define NS 6
#define NC 64
#define HF 44
#define WF 80
#define HW (HF * WF)       // 3520
#define NZ 16
#define NY 100
#define NX 100
#define XYZ (NX * NY * NZ) // 160000

typedef float v4f __attribute__((ext_vector_type(4)));  // for nontemporal store

// ---------------------------------------------------------------------------
// Kernel 1: transpose features (S,C,HF,WF) -> (S,HF*WF,C) so the 64 channels
// at one pixel are contiguous (256 B) for coalesced float4 gathers.
// float4 on both global sides; LDS tile stride 65 (2-way max = free).
// HW = 3520 = 55 * 64 exactly.
// ---------------------------------------------------------------------------
__global__ __launch_bounds__(256) void transpose_feat(
        const float* __restrict__ in, float* __restrict__ outT) {
    __shared__ float tile[64 * 65];
    int b = blockIdx.x;
    int s = b / 55;
    int hw0 = (b % 55) * 64;
    int t = threadIdx.x;
#pragma unroll
    for (int i = 0; i < 4; ++i) {
        int e = t + i * 256;          // 0..1023
        int c = e >> 4, wg = e & 15;  // 64 ch x 16 w-groups
        float4 f = *(const float4*)(in + ((size_t)(s * NC + c)) * HW + hw0 + wg * 4);
        tile[c * 65 + wg * 4 + 0] = f.x;
        tile[c * 65 + wg * 4 + 1] = f.y;
        tile[c * 65 + wg * 4 + 2] = f.z;
        tile[c * 65 + wg * 4 + 3] = f.w;
    }
    __syncthreads();
#pragma unroll
    for (int i = 0; i < 4; ++i) {
        int e = t + i * 256;
        int hwl = e >> 4, cg = e & 15;  // 64 hw x 16 c-groups
        float4 f;
        f.x = tile[(cg * 4 + 0) * 65 + hwl];
        f.y = tile[(cg * 4 + 1) * 65 + hwl];
        f.z = tile[(cg * 4 + 2) * 65 + hwl];
        f.w = tile[(cg * 4 + 3) * 65 + hwl];
        *(float4*)(outT + ((size_t)s * HW + hw0 + hwl) * NC + cg * 4) = f;
    }
}

// ---------------------------------------------------------------------------
// Kernel 2: main pooling. One block per (x,y) column: 16 z x 64 ch.
//  A1: t<6 build camera matrices.
//  A2: t<96 compute per-(z,cam) folded bilinear weights + offsets + flag.
//  A3: t<16 compact valid-cam lists per z (preserves s order).
//  B : thread=(z=t>>4, cg=t&15); branch-free loop over compacted list,
//      2-stage software pipeline (next cam's 4 float4 gathers in flight
//      while current FMAs retire).
//  C : LDS stage (stride 17) -> nontemporal coalesced float4 writes
//      (don't let 41 MB of output evict featT from L2).
// Block swizzle: 8 spatial regions of 50x25 columns; b&7 spreads regions
// across XCDs so each XCD's L2 sees a compact image sub-region.
// ---------------------------------------------------------------------------
template <bool TRANS>
__global__ __launch_bounds__(256) void volpool(
        const float* __restrict__ feat,
        const float* __restrict__ pix,
        const float* __restrict__ c0TX,
        float* __restrict__ out) {
    __shared__ float  mlds[NS * 16];
    __shared__ float4 wts[96];
    __shared__ int4   offs[96];
    __shared__ int    vflags[96];
    __shared__ int    vidx[NZ][NS];
    __shared__ int    nvalid[NZ];
    __shared__ float  ostage[NC * 17];

    int t = threadIdx.x;
    int b = blockIdx.x;
    // XCD-locality swizzle: region = b&7 (assumed XCD round-robin), 50x25 each
    int reg = b & 7;
    int r = b >> 3;                         // 0..1249
    int x = (reg & 1) * 50 + (r % 50);
    int y = (reg >> 1) * 25 + (r / 50);

    // ---- A1: camera matrices (rows 0..2 of pix_T_cam0, z_cam row) ----
    if (t < NS) {
        const float* T = c0TX + t * 16;
        float inv[4][4];
        for (int i = 0; i < 3; ++i) {
            for (int j = 0; j < 3; ++j) inv[i][j] = T[j * 4 + i];
            inv[i][3] = -(T[0 * 4 + i] * T[0 * 4 + 3] +
                          T[1 * 4 + i] * T[1 * 4 + 3] +
                          T[2 * 4 + i] * T[2 * 4 + 3]);
        }
        inv[3][0] = 0.f; inv[3][1] = 0.f; inv[3][2] = 0.f; inv[3][3] = 1.f;
        const float sx = (float)WF / 640.0f;
        const float sy = (float)HF / 352.0f;
        const float* K = pix + t * 16;
        float fp[3][4];
        for (int j = 0; j < 4; ++j) {
            fp[0][j] = sx * K[0 * 4 + j];
            fp[1][j] = sy * K[1 * 4 + j];
            fp[2][j] = K[2 * 4 + j];
        }
        float* M = mlds + t * 16;
        for (int i = 0; i < 3; ++i)
            for (int j = 0; j < 4; ++j) {
                float acc = 0.f;
                for (int k = 0; k < 4; ++k) acc += fp[i][k] * inv[k][j];
                M[i * 4 + j] = acc;
            }
        for (int j = 0; j < 4; ++j) M[12 + j] = inv[2][j];
    }
    __syncthreads();

    // ---- A2: per-(z,cam) projection params ----
    if (t < 96) {
        int s = t % NS, z = t / NS;
        const float* M = mlds + s * 16;
        float xw = -40.0f + 0.8f * ((float)x + 0.5f);
        float yw = -40.0f + 0.8f * ((float)y + 0.5f);
        float zw = -1.0f + 0.4f * ((float)z + 0.5f);
        float px = M[0] * xw + M[1] * yw + M[2]  * zw + M[3];
        float py = M[4] * xw + M[5] * yw + M[6]  * zw + M[7];
        float pz = M[8] * xw + M[9] * yw + M[10] * zw + M[11];
        float zc = M[12] * xw + M[13] * yw + M[14] * zw + M[15];
        float denom = fmaxf(pz, 1e-6f);
        float xp = px / denom, yp = py / denom;
        bool valid = (xp > -0.5f) & (xp < (float)WF - 0.5f) &
                     (yp > -0.5f) & (yp < (float)HF - 0.5f) & (zc > 0.0f);
        vflags[t] = valid ? 1 : 0;
        if (valid) {
            float xs = xp - 0.5f, ys = yp - 0.5f;
            float x0f = floorf(xs), y0f = floorf(ys);
            float wx1 = xs - x0f, wy1 = ys - y0f;
            float wx0 = 1.f - wx1, wy0 = 1.f - wy1;
            int x0 = (int)x0f, y0 = (int)y0f;
            int x1 = x0 + 1, y1 = y0 + 1;
            bool bx0 = (x0 >= 0) & (x0 < WF);
            bool bx1 = (x1 >= 0) & (x1 < WF);
            bool by0 = (y0 >= 0) & (y0 < HF);
            bool by1 = (y1 >= 0) & (y1 < HF);
            int x0c = min(max(x0, 0), WF - 1);
            int x1c = min(max(x1, 0), WF - 1);
            int y0c = min(max(y0, 0), HF - 1);
            int y1c = min(max(y1, 0), HF - 1);
            float4 w;
            w.x = wx0 * wy0 * (float)(bx0 & by0);
            w.y = wx1 * wy0 * (float)(bx1 & by0);
            w.z = wx0 * wy1 * (float)(bx0 & by1);
            w.w = wx1 * wy1 * (float)(bx1 & by1);
            int p00 = y0c * WF + x0c, p10 = y0c * WF + x1c;
            int p01 = y1c * WF + x0c, p11 = y1c * WF + x1c;
            int4 o;
            if (TRANS) {
                o.x = (s * HW + p00) * NC;
                o.y = (s * HW + p10) * NC;
                o.z = (s * HW + p01) * NC;
                o.w = (s * HW + p11) * NC;
            } else {
                o.x = s * NC * HW + p00;
                o.y = s * NC * HW + p10;
                o.z = s * NC * HW + p01;
                o.w = s * NC * HW + p11;
            }
            wts[t] = w;
            offs[t] = o;
        }
    }
    __syncthreads();

    // ---- A3: compact valid list per z (order-preserving) ----
    if (t < NZ) {
        int n = 0;
        for (int s = 0; s < NS; ++s) {
            int idx = t * NS + s;
            if (vflags[idx]) vidx[t][n++] = idx;
        }
        nvalid[t] = n;
    }
    __syncthreads();

    // ---- B: branch-free pipelined gather + bilinear + accumulate ----
    int cg = t & 15, z = t >> 4;
    int ch4 = cg << 2;
    float4 sum = make_float4(0.f, 0.f, 0.f, 0.f);
    float4 cnt = make_float4(0.f, 0.f, 0.f, 0.f);
    int nv = nvalid[z];
    if (nv > 0) {
        if (TRANS) {
            int idx = vidx[z][0];
            float4 w = wts[idx];
            int4 o = offs[idx];
            float4 f00 = *(const float4*)(feat + o.x + ch4);
            float4 f10 = *(const float4*)(feat + o.y + ch4);
            float4 f01 = *(const float4*)(feat + o.z + ch4);
            float4 f11 = *(const float4*)(feat + o.w + ch4);
            for (int j = 1; j < nv; ++j) {
                int idx2 = vidx[z][j];
                float4 w2 = wts[idx2];
                int4 o2 = offs[idx2];
                float4 g00 = *(const float4*)(feat + o2.x + ch4);
                float4 g10 = *(const float4*)(feat + o2.y + ch4);
                float4 g01 = *(const float4*)(feat + o2.z + ch4);
                float4 g11 = *(const float4*)(feat + o2.w + ch4);
                float vx = w.x * f00.x + w.y * f10.x + w.z * f01.x + w.w * f11.x;
                float vy = w.x * f00.y + w.y * f10.y + w.z * f01.y + w.w * f11.y;
                float vz = w.x * f00.z + w.y * f10.z + w.z * f01.z + w.w * f11.z;
                float vw = w.x * f00.w + w.y * f10.w + w.z * f01.w + w.w * f11.w;
                sum.x += vx; cnt.x += (vx != 0.0f) ? 1.0f : 0.0f;
                sum.y += vy; cnt.y += (vy != 0.0f) ? 1.0f : 0.0f;
                sum.z += vz; cnt.z += (vz != 0.0f) ? 1.0f : 0.0f;
                sum.w += vw; cnt.w += (vw != 0.0f) ? 1.0f : 0.0f;
                w = w2; f00 = g00; f10 = g10; f01 = g01; f11 = g11;
            }
            float vx = w.x * f00.x + w.y * f10.x + w.z * f01.x + w.w * f11.x;
            float vy = w.x * f00.y + w.y * f10.y + w.z * f01.y + w.w * f11.y;
            float vz = w.x * f00.z + w.y * f10.z + w.z * f01.z + w.w * f11.z;
            float vw = w.x * f00.w + w.y * f10.w + w.z * f01.w + w.w * f11.w;
            sum.x += vx; cnt.x += (vx != 0.0f) ? 1.0f : 0.0f;
            sum.y += vy; cnt.y += (vy != 0.0f) ? 1.0f : 0.0f;
            sum.z += vz; cnt.z += (vz != 0.0f) ? 1.0f : 0.0f;
            sum.w += vw; cnt.w += (vw != 0.0f) ? 1.0f : 0.0f;
        } else {
            for (int j = 0; j < nv; ++j) {
                int idx = vidx[z][j];
                float4 w = wts[idx];
                int4 o = offs[idx];
                int c0 = cg << 2;
                float4 f00, f10, f01, f11;
                f00.x = feat[o.x + (c0 + 0) * HW]; f00.y = feat[o.x + (c0 + 1) * HW];
                f00.z = feat[o.x + (c0 + 2) * HW]; f00.w = feat[o.x + (c0 + 3) * HW];
                f10.x = feat[o.y + (c0 + 0) * HW]; f10.y = feat[o.y + (c0 + 1) * HW];
                f10.z = feat[o.y + (c0 + 2) * HW]; f10.w = feat[o.y + (c0 + 3) * HW];
                f01.x = feat[o.z + (c0 + 0) * HW]; f01.y = feat[o.z + (c0 + 1) * HW];
                f01.z = feat[o.z + (c0 + 2) * HW]; f01.w = feat[o.z + (c0 + 3) * HW];
                f11.x = feat[o.w + (c0 + 0) * HW]; f11.y = feat[o.w + (c0 + 1) * HW];
                f11.z = feat[o.w + (c0 + 2) * HW]; f11.w = feat[o.w + (c0 + 3) * HW];
                float vx = w.x * f00.x + w.y * f10.x + w.z * f01.x + w.w * f11.x;
                float vy = w.x * f00.y + w.y * f10.y + w.z * f01.y + w.w * f11.y;
                float vz = w.x * f00.z + w.y * f10.z + w.z * f01.z + w.w * f11.z;
                float vw = w.x * f00.w + w.y * f10.w + w.z * f01.w + w.w * f11.w;
                sum.x += vx; cnt.x += (vx != 0.0f) ? 1.0f : 0.0f;
                sum.y += vy; cnt.y += (vy != 0.0f) ? 1.0f : 0.0f;
                sum.z += vz; cnt.z += (vz != 0.0f) ? 1.0f : 0.0f;
                sum.w += vw; cnt.w += (vw != 0.0f) ? 1.0f : 0.0f;
            }
        }
    }
    ostage[(ch4 + 0) * 17 + z] = sum.x / (cnt.x + 1e-6f);
    ostage[(ch4 + 1) * 17 + z] = sum.y / (cnt.y + 1e-6f);
    ostage[(ch4 + 2) * 17 + z] = sum.z / (cnt.z + 1e-6f);
    ostage[(ch4 + 3) * 17 + z] = sum.w / (cnt.w + 1e-6f);
    __syncthreads();

    // ---- C: nontemporal coalesced float4 write: out[((c*NX+x)*NY+y)*NZ+z] ----
    int c = t >> 2, zq = t & 3;
    v4f v4;
    v4.x = ostage[c * 17 + zq * 4 + 0];
    v4.y = ostage[c * 17 + zq * 4 + 1];
    v4.z = ostage[c * 17 + zq * 4 + 2];
    v4.w = ostage[c * 17 + zq * 4 + 3];
    float* o = out + (size_t)c * XYZ + ((size_t)x * NY + y) * NZ + zq * 4;
    __builtin_nontemporal_store(v4, (v4f*)o);
}

// ---------------------------------------------------------------------------
extern "C" void kernel_launch(void* const* d_in, const int* in_sizes, int n_in,
                              void* d_out, int out_size, void* d_ws, size_t ws_size,
                              hipStream_t stream) {
    const float* features = (const float*)d_in[0];
    const float* pix      = (const float*)d_in[1];
    const float* c0TX     = (const float*)d_in[2];
    float* out   = (float*)d_out;
    float* featT = (float*)d_ws;
    size_t need = sizeof(float) * (size_t)NS * HW * NC;

    if (ws_size >= need) {
        hipLaunchKernelGGL(transpose_feat, dim3(NS * 55), dim3(256), 0, stream,
                           features, featT);
        hipLaunchKernelGGL((volpool<true>), dim3(NX * NY), dim3(256), 0, stream,
                           featT, pix, c0TX, out);
    } else {
        hipLaunchKernelGGL((volpool<false>), dim3(NX * NY), dim3(256), 0, stream,
                           features, pix, c0TX, out);
    }
}